// Round 11
// baseline (59.077 us; speedup 1.0000x reference)
//
#include <hip/hip_runtime.h>

#define CLS 8
#define BATCH 8
#define SPAN 2048                    // px per block -> 128 chunks per batch, 1024 blocks
#define NSLICE 8
#define LOG2E 1.442695040888963f
#define LN2   0.693147180559945f

typedef float f32x4 __attribute__((ext_vector_type(4)));
typedef int   i32x4 __attribute__((ext_vector_type(4)));

struct WS {
    float    S[NSLICE][BATCH][64];   // S[b][c*8+k] = sum_{p: t=k} pred[c][p]
    float    n[NSLICE][BATCH][CLS];  // class pixel counts
    float    lse[NSLICE];            // natural-log lse sum
    unsigned cnt;                    // completion ticket
};

__device__ __forceinline__ float wave_reduce(float v) {
#pragma unroll
    for (int off = 32; off > 0; off >>= 1) v += __shfl_xor(v, off);
    return v;
}

// asm-pinned loads: compiler cannot sink these past the explicit vmcnt drain
#define GLDF(dst, ptr) asm volatile("global_load_dwordx4 %0, %1, off" : "=v"(dst) : "v"(ptr))
#define GLDI(dst, ptr) asm volatile("global_load_dwordx4 %0, %1, off" : "=v"(dst) : "v"(ptr))

__global__ __launch_bounds__(256, 2) void jce_fused(
    const float* __restrict__ pred, const int* __restrict__ tgt,
    const float* __restrict__ w, float* __restrict__ out,
    WS* ws, int N)
{
    const int tid   = threadIdx.x;
    const int b     = blockIdx.x & (BATCH - 1);
    const int chunk = blockIdx.x >> 3;          // 0..127
    const int lane  = tid & 63;
    const int wv    = tid >> 6;                 // 4 waves
    const float* pb = pred + (size_t)b * CLS * N + chunk * SPAN;
    const int*   tb = tgt  + (size_t)b * N + chunk * SPAN;

    // ---- issue burst: 18 loads, ~18KB per wave in flight ----
    i32x4 t0, t1;
    f32x4 p0a, p0b, p1a, p1b, p2a, p2b, p3a, p3b;
    f32x4 p4a, p4b, p5a, p5b, p6a, p6b, p7a, p7b;

    GLDI(t0, tb + tid * 4);
    GLDI(t1, tb + 1024 + tid * 4);
#define ISSUE(A, B, c) do {                                       \
        GLDF(A, pb + (size_t)(c) * N + tid * 4);                  \
        GLDF(B, pb + (size_t)(c) * N + 1024 + tid * 4);           \
    } while (0)
    ISSUE(p0a, p0b, 0); ISSUE(p1a, p1b, 1); ISSUE(p2a, p2b, 2); ISSUE(p3a, p3b, 3);
    ISSUE(p4a, p4b, 4); ISSUE(p5a, p5b, 5); ISSUE(p6a, p6b, 6); ISSUE(p7a, p7b, 7);
#undef ISSUE

    asm volatile("s_waitcnt vmcnt(0)" ::: "memory");
    __builtin_amdgcn_sched_barrier(0);   // rule #18: keep consumers below the wait

    // ---- compute on registers ----
    float acc[64];                       // acc[c*8+k] = sum_{p: t=k} pred[c][p]
#pragma unroll
    for (int j = 0; j < 64; ++j) acc[j] = 0.f;
    float s[8];
#pragma unroll
    for (int j = 0; j < 8; ++j) s[j] = 0.f;

#define ACCC(X0, X1, c) do {                                                    \
        _Pragma("unroll")                                                       \
        for (int _e = 0; _e < 4; ++_e) {                                        \
            const float _p0 = (X0)[_e];                                         \
            const int   _v0 = t0[_e];                                           \
            s[_e] += exp2f(_p0 * LOG2E);                                        \
            _Pragma("unroll")                                                   \
            for (int _k = 0; _k < CLS; ++_k)                                    \
                acc[(c) * 8 + _k] += (_v0 == _k) ? _p0 : 0.f;                   \
            const float _p1 = (X1)[_e];                                         \
            const int   _v1 = t1[_e];                                           \
            s[4 + _e] += exp2f(_p1 * LOG2E);                                    \
            _Pragma("unroll")                                                   \
            for (int _k = 0; _k < CLS; ++_k)                                    \
                acc[(c) * 8 + _k] += (_v1 == _k) ? _p1 : 0.f;                   \
        }                                                                       \
    } while (0)

    ACCC(p0a, p0b, 0); ACCC(p1a, p1b, 1); ACCC(p2a, p2b, 2); ACCC(p3a, p3b, 3);
    ACCC(p4a, p4b, 4); ACCC(p5a, p5b, 5); ACCC(p6a, p6b, 6); ACCC(p7a, p7b, 7);
#undef ACCC

    float lsum = 0.f;
#pragma unroll
    for (int j = 0; j < 8; ++j) lsum += log2f(s[j]);

    // class counts via ballot (wave-uniform)
    int cntk[CLS];
#pragma unroll
    for (int k = 0; k < CLS; ++k) {
        int c8 = 0;
#pragma unroll
        for (int e = 0; e < 4; ++e) {
            c8 += __popcll(__ballot(t0[e] == k));
            c8 += __popcll(__ballot(t1[e] == k));
        }
        cntk[k] = c8;
    }

    // split-vector butterfly: lane l ends holding wave-total of entry bitrev6(l)
#pragma unroll
    for (int s6 = 0; s6 < 6; ++s6) {
        const int d = 1 << s6;
        const int half = 32 >> s6;
        const bool hi = (lane & d) != 0;
#pragma unroll
        for (int j = 0; j < half; ++j) {
            const float keep = hi ? acc[j + half] : acc[j];
            const float send = hi ? acc[j] : acc[j + half];
            acc[j] = keep + __shfl_xor(send, d);
        }
    }
    const int e6 = ((lane & 1) << 5) | ((lane & 2) << 3) | ((lane & 4) << 1) |
                   ((lane & 8) >> 1) | ((lane & 16) >> 3) | ((lane & 32) >> 5);

    __shared__ float redS[4][64];
    __shared__ float redl[4];
    __shared__ int   redc[4][CLS];

    redS[wv][e6] = acc[0];
    const float lw = wave_reduce(lsum);
    if (lane == 0) {
        redl[wv] = lw;
#pragma unroll
        for (int k = 0; k < CLS; ++k) redc[wv][k] = cntk[k];
    }
    __syncthreads();

    const int sl = chunk & (NSLICE - 1);
    if (tid < 64) {
        const float v = redS[0][tid] + redS[1][tid] + redS[2][tid] + redS[3][tid];
        atomicAdd(&ws->S[sl][b][tid], v);
    } else if (tid < 64 + CLS) {
        const int k = tid - 64;
        const float v = (float)(redc[0][k] + redc[1][k] + redc[2][k] + redc[3][k]);
        atomicAdd(&ws->n[sl][b][k], v);
    } else if (tid == 64 + CLS) {
        atomicAdd(&ws->lse[sl], (redl[0] + redl[1] + redl[2] + redl[3]) * LN2);
    }

    // ---- last-block-done epilogue ----
    __syncthreads();
    __shared__ int lastFlag;
    if (tid == 0) {
        __threadfence();
        const unsigned t = atomicAdd(&ws->cnt, 1u);
        lastFlag = (t == gridDim.x - 1) ? 1 : 0;
    }
    __syncthreads();
    if (!lastFlag) return;
    __threadfence();

    __shared__ float epi[576];             // eS[8][64] + eN[8][8]
    __shared__ float eLse, eCe;
    for (int j = tid; j < 577; j += 256) {
        float a = 0.f;
        if (j < 512) {
            const int bb = j >> 6, ee = j & 63;
#pragma unroll
            for (int s8 = 0; s8 < NSLICE; ++s8) a += atomicAdd(&ws->S[s8][bb][ee], 0.f);
            epi[j] = a;
        } else if (j < 576) {
            const int q = j - 512, bb = q >> 3, k = q & 7;
#pragma unroll
            for (int s8 = 0; s8 < NSLICE; ++s8) a += atomicAdd(&ws->n[s8][bb][k], 0.f);
            epi[j] = a;
        } else {
#pragma unroll
            for (int s8 = 0; s8 < NSLICE; ++s8) a += atomicAdd(&ws->lse[s8], 0.f);
            eLse = a;
        }
    }
    __syncthreads();

    // ce = (sum lse - sum_b trace(S_b)) / (B*N)
    if (tid < 64) {
        const int bb = tid >> 3, kk = tid & 7;
        float tv = epi[bb * 64 + kk * 9];
        tv = wave_reduce(tv);
        if (tid == 0) eCe = (eLse - tv) / ((float)BATCH * (float)N);
    }
    __syncthreads();

    // j[b] = -sum_{i!=k} w[i,k]*log(0.5 + 0.5*(A[i,i]-A[i,k])); out = j + ce
    if (wv < 4) {
#pragma unroll
        for (int r = 0; r < 2; ++r) {
            const int bb = wv * 2 + r;         // 4 waves x 2 batches
            const int i = lane >> 3, k = lane & 7;
            const float A    = epi[bb * 64 + lane]  / epi[512 + bb * 8 + k];
            const float diag = epi[bb * 64 + i * 9] / epi[512 + bb * 8 + i];
            float term = 0.f;
            if (i != k)
                term = w[lane] * (log2f(0.5f + 0.5f * (diag - A)) * LN2);
            term = wave_reduce(term);
            if (lane == 0) out[bb] = -term + eCe;
        }
    }
}

extern "C" void kernel_launch(void* const* d_in, const int* in_sizes, int n_in,
                              void* d_out, int out_size, void* d_ws, size_t ws_size,
                              hipStream_t stream) {
    const float* pred = (const float*)d_in[0];
    const int*   tgt  = (const int*)d_in[1];
    const float* w    = (const float*)d_in[2];
    float* out = (float*)d_out;

    const int N = in_sizes[1] / BATCH;        // H*W = 262144
    WS* ws = (WS*)d_ws;

    hipMemsetAsync(ws, 0, sizeof(WS), stream);
    jce_fused<<<dim3(BATCH * (N / SPAN)), dim3(256), 0, stream>>>(pred, tgt, w, out, ws, N);
}

// Round 12
// 57.313 us; speedup vs baseline: 1.0308x; 1.0308x over previous
//
#include <hip/hip_runtime.h>

#define CLS 8
#define BATCH 8
#define SPAN 2048                    // px per block -> 128 chunks per batch, 1024 blocks
#define NSLICE 8
#define LOG2E 1.442695040888963f
#define LN2   0.693147180559945f

typedef float f32x4 __attribute__((ext_vector_type(4)));
typedef int   i32x4 __attribute__((ext_vector_type(4)));

struct WS {
    float    S[NSLICE][BATCH][64];   // S[b][c*8+k] = sum_{p: t=k} pred[c][p]
    float    n[NSLICE][BATCH][CLS];  // class pixel counts
    float    lse[NSLICE];            // natural-log lse sum
    unsigned cnt;                    // completion ticket
};

__device__ __forceinline__ float wave_reduce(float v) {
#pragma unroll
    for (int off = 32; off > 0; off >>= 1) v += __shfl_xor(v, off);
    return v;
}

// asm-pinned loads: compiler cannot sink these past the explicit vmcnt drain
#define GLDF(dst, ptr) asm volatile("global_load_dwordx4 %0, %1, off" : "=v"(dst) : "v"(ptr))
#define GLDI(dst, ptr) asm volatile("global_load_dwordx4 %0, %1, off" : "=v"(dst) : "v"(ptr))

__global__ __launch_bounds__(256, 2) void jce_fused(
    const float* __restrict__ pred, const int* __restrict__ tgt,
    const float* __restrict__ w, float* __restrict__ out,
    WS* ws, int N)
{
    const int tid   = threadIdx.x;
    const int b     = blockIdx.x & (BATCH - 1);
    const int chunk = blockIdx.x >> 3;          // 0..127
    const int lane  = tid & 63;
    const int wv    = tid >> 6;                 // 4 waves
    const float* pb = pred + (size_t)b * CLS * N + chunk * SPAN;
    const int*   tb = tgt  + (size_t)b * N + chunk * SPAN;

    // ---- issue burst: 18 loads, ~18KB per wave in flight ----
    i32x4 t0, t1;
    f32x4 p0a, p0b, p1a, p1b, p2a, p2b, p3a, p3b;
    f32x4 p4a, p4b, p5a, p5b, p6a, p6b, p7a, p7b;

    GLDI(t0, tb + tid * 4);
    GLDI(t1, tb + 1024 + tid * 4);
#define ISSUE(A, B, c) do {                                       \
        GLDF(A, pb + (size_t)(c) * N + tid * 4);                  \
        GLDF(B, pb + (size_t)(c) * N + 1024 + tid * 4);           \
    } while (0)
    ISSUE(p0a, p0b, 0); ISSUE(p1a, p1b, 1); ISSUE(p2a, p2b, 2); ISSUE(p3a, p3b, 3);
    ISSUE(p4a, p4b, 4); ISSUE(p5a, p5b, 5); ISSUE(p6a, p6b, 6); ISSUE(p7a, p7b, 7);
#undef ISSUE

    asm volatile("s_waitcnt vmcnt(0)" ::: "memory");
    __builtin_amdgcn_sched_barrier(0);   // rule #18: keep consumers below the wait

    // ---- compute on registers ----
    float acc[64];                       // acc[c*8+k] = sum_{p: t=k} pred[c][p]
#pragma unroll
    for (int j = 0; j < 64; ++j) acc[j] = 0.f;
    float s[8];
#pragma unroll
    for (int j = 0; j < 8; ++j) s[j] = 0.f;

#define ACCC(X0, X1, c) do {                                                    \
        _Pragma("unroll")                                                       \
        for (int _e = 0; _e < 4; ++_e) {                                        \
            const float _p0 = (X0)[_e];                                         \
            const int   _v0 = t0[_e];                                           \
            s[_e] += exp2f(_p0 * LOG2E);                                        \
            _Pragma("unroll")                                                   \
            for (int _k = 0; _k < CLS; ++_k)                                    \
                acc[(c) * 8 + _k] += (_v0 == _k) ? _p0 : 0.f;                   \
            const float _p1 = (X1)[_e];                                         \
            const int   _v1 = t1[_e];                                           \
            s[4 + _e] += exp2f(_p1 * LOG2E);                                    \
            _Pragma("unroll")                                                   \
            for (int _k = 0; _k < CLS; ++_k)                                    \
                acc[(c) * 8 + _k] += (_v1 == _k) ? _p1 : 0.f;                   \
        }                                                                       \
    } while (0)

    ACCC(p0a, p0b, 0); ACCC(p1a, p1b, 1); ACCC(p2a, p2b, 2); ACCC(p3a, p3b, 3);
    ACCC(p4a, p4b, 4); ACCC(p5a, p5b, 5); ACCC(p6a, p6b, 6); ACCC(p7a, p7b, 7);
#undef ACCC

    float lsum = 0.f;
#pragma unroll
    for (int j = 0; j < 8; ++j) lsum += log2f(s[j]);

    // class counts via ballot (wave-uniform)
    int cntk[CLS];
#pragma unroll
    for (int k = 0; k < CLS; ++k) {
        int c8 = 0;
#pragma unroll
        for (int e = 0; e < 4; ++e) {
            c8 += __popcll(__ballot(t0[e] == k));
            c8 += __popcll(__ballot(t1[e] == k));
        }
        cntk[k] = c8;
    }

    // split-vector butterfly: lane l ends holding wave-total of entry bitrev6(l)
#pragma unroll
    for (int s6 = 0; s6 < 6; ++s6) {
        const int d = 1 << s6;
        const int half = 32 >> s6;
        const bool hi = (lane & d) != 0;
#pragma unroll
        for (int j = 0; j < half; ++j) {
            const float keep = hi ? acc[j + half] : acc[j];
            const float send = hi ? acc[j] : acc[j + half];
            acc[j] = keep + __shfl_xor(send, d);
        }
    }
    const int e6 = ((lane & 1) << 5) | ((lane & 2) << 3) | ((lane & 4) << 1) |
                   ((lane & 8) >> 1) | ((lane & 16) >> 3) | ((lane & 32) >> 5);

    __shared__ float redS[4][64];
    __shared__ float redl[4];
    __shared__ int   redc[4][CLS];

    redS[wv][e6] = acc[0];
    const float lw = wave_reduce(lsum);
    if (lane == 0) {
        redl[wv] = lw;
#pragma unroll
        for (int k = 0; k < CLS; ++k) redc[wv][k] = cntk[k];
    }
    __syncthreads();

    const int sl = chunk & (NSLICE - 1);
    if (tid < 64) {
        const float v = redS[0][tid] + redS[1][tid] + redS[2][tid] + redS[3][tid];
        atomicAdd(&ws->S[sl][b][tid], v);
    } else if (tid < 64 + CLS) {
        const int k = tid - 64;
        const float v = (float)(redc[0][k] + redc[1][k] + redc[2][k] + redc[3][k]);
        atomicAdd(&ws->n[sl][b][k], v);
    } else if (tid == 64 + CLS) {
        atomicAdd(&ws->lse[sl], (redl[0] + redl[1] + redl[2] + redl[3]) * LN2);
    }

    // ---- last-block-done epilogue ----
    __syncthreads();
    __shared__ int lastFlag;
    if (tid == 0) {
        __threadfence();
        const unsigned t = atomicAdd(&ws->cnt, 1u);
        lastFlag = (t == gridDim.x - 1) ? 1 : 0;
    }
    __syncthreads();
    if (!lastFlag) return;
    __threadfence();

    __shared__ float epi[576];             // eS[8][64] + eN[8][8]
    __shared__ float eLse, eCe;
    for (int j = tid; j < 577; j += 256) {
        float a = 0.f;
        if (j < 512) {
            const int bb = j >> 6, ee = j & 63;
#pragma unroll
            for (int s8 = 0; s8 < NSLICE; ++s8) a += atomicAdd(&ws->S[s8][bb][ee], 0.f);
            epi[j] = a;
        } else if (j < 576) {
            const int q = j - 512, bb = q >> 3, k = q & 7;
#pragma unroll
            for (int s8 = 0; s8 < NSLICE; ++s8) a += atomicAdd(&ws->n[s8][bb][k], 0.f);
            epi[j] = a;
        } else {
#pragma unroll
            for (int s8 = 0; s8 < NSLICE; ++s8) a += atomicAdd(&ws->lse[s8], 0.f);
            eLse = a;
        }
    }
    __syncthreads();

    // ce = (sum lse - sum_b trace(S_b)) / (B*N)
    if (tid < 64) {
        const int bb = tid >> 3, kk = tid & 7;
        float tv = epi[bb * 64 + kk * 9];
        tv = wave_reduce(tv);
        if (tid == 0) eCe = (eLse - tv) / ((float)BATCH * (float)N);
    }
    __syncthreads();

    // j[b] = -sum_{i!=k} w[i,k]*log(0.5 + 0.5*(A[i,i]-A[i,k])); out = j + ce
    if (wv < 4) {
#pragma unroll
        for (int r = 0; r < 2; ++r) {
            const int bb = wv * 2 + r;         // 4 waves x 2 batches
            const int i = lane >> 3, k = lane & 7;
            const float A    = epi[bb * 64 + lane]  / epi[512 + bb * 8 + k];
            const float diag = epi[bb * 64 + i * 9] / epi[512 + bb * 8 + i];
            float term = 0.f;
            if (i != k)
                term = w[lane] * (log2f(0.5f + 0.5f * (diag - A)) * LN2);
            term = wave_reduce(term);
            if (lane == 0) out[bb] = -term + eCe;
        }
    }
}

extern "C" void kernel_launch(void* const* d_in, const int* in_sizes, int n_in,
                              void* d_out, int out_size, void* d_ws, size_t ws_size,
                              hipStream_t stream) {
    const float* pred = (const float*)d_in[0];
    const int*   tgt  = (const int*)d_in[1];
    const float* w    = (const float*)d_in[2];
    float* out = (float*)d_out;

    const int N = in_sizes[1] / BATCH;        // H*W = 262144
    WS* ws = (WS*)d_ws;

    hipMemsetAsync(ws, 0, sizeof(WS), stream);
    jce_fused<<<dim3(BATCH * (N / SPAN)), dim3(256), 0, stream>>>(pred, tgt, w, out, ws, N);
}

// Round 13
// 56.112 us; speedup vs baseline: 1.0528x; 1.0214x over previous
//
#include <hip/hip_runtime.h>

#define CLS 8
#define BATCH 8
#define SPAN 2048                    // px per block -> 128 chunks per batch, 1024 blocks
#define NSLICE 8
#define LOG2E 1.442695040888963f
#define LN2   0.693147180559945f

typedef float f32x4 __attribute__((ext_vector_type(4)));
typedef int   i32x4 __attribute__((ext_vector_type(4)));

struct WS {
    float    S[NSLICE][BATCH][64];   // S[b][c*8+k] = sum_{p: t=k} pred[c][p]
    float    n[NSLICE][BATCH][CLS];  // class pixel counts
    float    lse[NSLICE];            // natural-log lse sum
    unsigned cnt;                    // completion ticket
};

__device__ __forceinline__ float wave_reduce(float v) {
#pragma unroll
    for (int off = 32; off > 0; off >>= 1) v += __shfl_xor(v, off);
    return v;
}

// asm-pinned loads: compiler cannot sink these past the explicit vmcnt drain
#define GLDF(dst, ptr) asm volatile("global_load_dwordx4 %0, %1, off" : "=v"(dst) : "v"(ptr))
#define GLDI(dst, ptr) asm volatile("global_load_dwordx4 %0, %1, off" : "=v"(dst) : "v"(ptr))

__global__ __launch_bounds__(256, 2) void jce_fused(
    const float* __restrict__ pred, const int* __restrict__ tgt,
    const float* __restrict__ w, float* __restrict__ out,
    WS* ws, int N)
{
    const int tid   = threadIdx.x;
    const int b     = blockIdx.x & (BATCH - 1);
    const int chunk = blockIdx.x >> 3;          // 0..127
    const int lane  = tid & 63;
    const int wv    = tid >> 6;                 // 4 waves
    const float* pb = pred + (size_t)b * CLS * N + chunk * SPAN;
    const int*   tb = tgt  + (size_t)b * N + chunk * SPAN;

    // ---- issue burst: 18 loads, ~18KB per wave in flight ----
    i32x4 t0, t1;
    f32x4 p0a, p0b, p1a, p1b, p2a, p2b, p3a, p3b;
    f32x4 p4a, p4b, p5a, p5b, p6a, p6b, p7a, p7b;

    GLDI(t0, tb + tid * 4);
    GLDI(t1, tb + 1024 + tid * 4);
#define ISSUE(A, B, c) do {                                       \
        GLDF(A, pb + (size_t)(c) * N + tid * 4);                  \
        GLDF(B, pb + (size_t)(c) * N + 1024 + tid * 4);           \
    } while (0)
    ISSUE(p0a, p0b, 0); ISSUE(p1a, p1b, 1); ISSUE(p2a, p2b, 2); ISSUE(p3a, p3b, 3);
    ISSUE(p4a, p4b, 4); ISSUE(p5a, p5b, 5); ISSUE(p6a, p6b, 6); ISSUE(p7a, p7b, 7);
#undef ISSUE

    asm volatile("s_waitcnt vmcnt(0)" ::: "memory");
    __builtin_amdgcn_sched_barrier(0);   // rule #18: keep consumers below the wait

    // ---- compute on registers ----
    float acc[64];                       // acc[c*8+k] = sum_{p: t=k} pred[c][p]
#pragma unroll
    for (int j = 0; j < 64; ++j) acc[j] = 0.f;
    float s[8];
#pragma unroll
    for (int j = 0; j < 8; ++j) s[j] = 0.f;

#define ACCC(X0, X1, c) do {                                                    \
        _Pragma("unroll")                                                       \
        for (int _e = 0; _e < 4; ++_e) {                                        \
            const float _p0 = (X0)[_e];                                         \
            const int   _v0 = t0[_e];                                           \
            s[_e] += exp2f(_p0 * LOG2E);                                        \
            _Pragma("unroll")                                                   \
            for (int _k = 0; _k < CLS; ++_k)                                    \
                acc[(c) * 8 + _k] += (_v0 == _k) ? _p0 : 0.f;                   \
            const float _p1 = (X1)[_e];                                         \
            const int   _v1 = t1[_e];                                           \
            s[4 + _e] += exp2f(_p1 * LOG2E);                                    \
            _Pragma("unroll")                                                   \
            for (int _k = 0; _k < CLS; ++_k)                                    \
                acc[(c) * 8 + _k] += (_v1 == _k) ? _p1 : 0.f;                   \
        }                                                                       \
    } while (0)

    ACCC(p0a, p0b, 0); ACCC(p1a, p1b, 1); ACCC(p2a, p2b, 2); ACCC(p3a, p3b, 3);
    ACCC(p4a, p4b, 4); ACCC(p5a, p5b, 5); ACCC(p6a, p6b, 6); ACCC(p7a, p7b, 7);
#undef ACCC

    float lsum = 0.f;
#pragma unroll
    for (int j = 0; j < 8; ++j) lsum += log2f(s[j]);

    // class counts via ballot (wave-uniform)
    int cntk[CLS];
#pragma unroll
    for (int k = 0; k < CLS; ++k) {
        int c8 = 0;
#pragma unroll
        for (int e = 0; e < 4; ++e) {
            c8 += __popcll(__ballot(t0[e] == k));
            c8 += __popcll(__ballot(t1[e] == k));
        }
        cntk[k] = c8;
    }

    // split-vector butterfly: lane l ends holding wave-total of entry bitrev6(l)
#pragma unroll
    for (int s6 = 0; s6 < 6; ++s6) {
        const int d = 1 << s6;
        const int half = 32 >> s6;
        const bool hi = (lane & d) != 0;
#pragma unroll
        for (int j = 0; j < half; ++j) {
            const float keep = hi ? acc[j + half] : acc[j];
            const float send = hi ? acc[j] : acc[j + half];
            acc[j] = keep + __shfl_xor(send, d);
        }
    }
    const int e6 = ((lane & 1) << 5) | ((lane & 2) << 3) | ((lane & 4) << 1) |
                   ((lane & 8) >> 1) | ((lane & 16) >> 3) | ((lane & 32) >> 5);

    __shared__ float redS[4][64];
    __shared__ float redl[4];
    __shared__ int   redc[4][CLS];

    redS[wv][e6] = acc[0];
    const float lw = wave_reduce(lsum);
    if (lane == 0) {
        redl[wv] = lw;
#pragma unroll
        for (int k = 0; k < CLS; ++k) redc[wv][k] = cntk[k];
    }
    __syncthreads();

    const int sl = chunk & (NSLICE - 1);
    if (tid < 64) {
        const float v = redS[0][tid] + redS[1][tid] + redS[2][tid] + redS[3][tid];
        atomicAdd(&ws->S[sl][b][tid], v);
    } else if (tid < 64 + CLS) {
        const int k = tid - 64;
        const float v = (float)(redc[0][k] + redc[1][k] + redc[2][k] + redc[3][k]);
        atomicAdd(&ws->n[sl][b][k], v);
    } else if (tid == 64 + CLS) {
        atomicAdd(&ws->lse[sl], (redl[0] + redl[1] + redl[2] + redl[3]) * LN2);
    }

    // ---- last-block-done epilogue ----
    __syncthreads();
    __shared__ int lastFlag;
    if (tid == 0) {
        __threadfence();
        const unsigned t = atomicAdd(&ws->cnt, 1u);
        lastFlag = (t == gridDim.x - 1) ? 1 : 0;
    }
    __syncthreads();
    if (!lastFlag) return;
    __threadfence();

    __shared__ float epi[576];             // eS[8][64] + eN[8][8]
    __shared__ float eLse, eCe;
    for (int j = tid; j < 577; j += 256) {
        float a = 0.f;
        if (j < 512) {
            const int bb = j >> 6, ee = j & 63;
#pragma unroll
            for (int s8 = 0; s8 < NSLICE; ++s8) a += atomicAdd(&ws->S[s8][bb][ee], 0.f);
            epi[j] = a;
        } else if (j < 576) {
            const int q = j - 512, bb = q >> 3, k = q & 7;
#pragma unroll
            for (int s8 = 0; s8 < NSLICE; ++s8) a += atomicAdd(&ws->n[s8][bb][k], 0.f);
            epi[j] = a;
        } else {
#pragma unroll
            for (int s8 = 0; s8 < NSLICE; ++s8) a += atomicAdd(&ws->lse[s8], 0.f);
            eLse = a;
        }
    }
    __syncthreads();

    // ce = (sum lse - sum_b trace(S_b)) / (B*N)
    if (tid < 64) {
        const int bb = tid >> 3, kk = tid & 7;
        float tv = epi[bb * 64 + kk * 9];
        tv = wave_reduce(tv);
        if (tid == 0) eCe = (eLse - tv) / ((float)BATCH * (float)N);
    }
    __syncthreads();

    // j[b] = -sum_{i!=k} w[i,k]*log(0.5 + 0.5*(A[i,i]-A[i,k])); out = j + ce
    if (wv < 4) {
#pragma unroll
        for (int r = 0; r < 2; ++r) {
            const int bb = wv * 2 + r;         // 4 waves x 2 batches
            const int i = lane >> 3, k = lane & 7;
            const float A    = epi[bb * 64 + lane]  / epi[512 + bb * 8 + k];
            const float diag = epi[bb * 64 + i * 9] / epi[512 + bb * 8 + i];
            float term = 0.f;
            if (i != k)
                term = w[lane] * (log2f(0.5f + 0.5f * (diag - A)) * LN2);
            term = wave_reduce(term);
            if (lane == 0) out[bb] = -term + eCe;
        }
    }
}

extern "C" void kernel_launch(void* const* d_in, const int* in_sizes, int n_in,
                              void* d_out, int out_size, void* d_ws, size_t ws_size,
                              hipStream_t stream) {
    const float* pred = (const float*)d_in[0];
    const int*   tgt  = (const int*)d_in[1];
    const float* w    = (const float*)d_in[2];
    float* out = (float*)d_out;

    const int N = in_sizes[1] / BATCH;        // H*W = 262144
    WS* ws = (WS*)d_ws;

    hipMemsetAsync(ws, 0, sizeof(WS), stream);
    jce_fused<<<dim3(BATCH * (N / SPAN)), dim3(256), 0, stream>>>(pred, tgt, w, out, ws, N);
}

// Round 14
// 38.284 us; speedup vs baseline: 1.5431x; 1.4657x over previous
//
#include <hip/hip_runtime.h>

#define CLS 8
#define BATCH 8
#define SPAN 2048                 // px per block -> 128 chunks/batch, 1024 blocks
#define SLOTF 80                  // floats per block slot (73 used, padded)
#define LOG2E 1.442695040888963f
#define LN2   0.693147180559945f

#define F4C(v, e) ((e) == 0 ? (v).x : (e) == 1 ? (v).y : (e) == 2 ? (v).z : (v).w)

__device__ __forceinline__ float wave_reduce(float v) {
#pragma unroll
    for (int off = 32; off > 0; off >>= 1) v += __shfl_xor(v, off);
    return v;
}

// ---------------- main: one pass over pred/tgt; NO atomics, NO fences, NO ticket.
// Per-block partials (64 S + 8 counts + 1 lse) -> private slot, plain stores. ----
__global__ __launch_bounds__(256, 4) void jce_main(
    const float* __restrict__ pred, const int* __restrict__ tgt,
    float* __restrict__ part, int N)
{
    const int tid   = threadIdx.x;
    const int b     = blockIdx.x & (BATCH - 1);
    const int chunk = blockIdx.x >> 3;          // 0..127
    const int lane  = tid & 63;
    const int wv    = tid >> 6;
    const float* pb = pred + (size_t)b * CLS * N + chunk * SPAN;
    const int*   tb = tgt  + (size_t)b * N + chunk * SPAN;

    // this thread's 8 targets, held in registers the whole kernel
    const int4 t0 = *reinterpret_cast<const int4*>(tb + tid * 4);
    const int4 t1 = *reinterpret_cast<const int4*>(tb + 1024 + tid * 4);

    float acc[64];                              // acc[c*8+k] = sum_{p: t=k} pred[c][p]
#pragma unroll
    for (int j = 0; j < 64; ++j) acc[j] = 0.f;
    float s[8];                                 // per-pixel running exp2 sums
#pragma unroll
    for (int j = 0; j < 8; ++j) s[j] = 0.f;

    float4 a0, a1, c0, c1;

#define LDC(X0, X1, c) do {                                                          \
        (X0) = *reinterpret_cast<const float4*>(pb + (size_t)(c) * N + tid * 4);     \
        (X1) = *reinterpret_cast<const float4*>(pb + (size_t)(c) * N + 1024 + tid * 4); \
    } while (0)

#define ACCC(X0, X1, c) do {                                                         \
        _Pragma("unroll")                                                            \
        for (int _e = 0; _e < 4; ++_e) {                                             \
            const float _p0 = F4C((X0), _e);                                         \
            const int   _v0 = F4C(t0, _e);                                           \
            s[_e] += exp2f(_p0 * LOG2E);                                             \
            _Pragma("unroll")                                                        \
            for (int _k = 0; _k < CLS; ++_k)                                         \
                acc[(c) * 8 + _k] += (_v0 == _k) ? _p0 : 0.f;                        \
            const float _p1 = F4C((X1), _e);                                         \
            const int   _v1 = F4C(t1, _e);                                           \
            s[4 + _e] += exp2f(_p1 * LOG2E);                                         \
            _Pragma("unroll")                                                        \
            for (int _k = 0; _k < CLS; ++_k)                                         \
                acc[(c) * 8 + _k] += (_v1 == _k) ? _p1 : 0.f;                        \
        }                                                                            \
    } while (0)

    LDC(a0, a1, 0);
    LDC(c0, c1, 1);
    ACCC(a0, a1, 0); LDC(a0, a1, 2);
    ACCC(c0, c1, 1); LDC(c0, c1, 3);
    ACCC(a0, a1, 2); LDC(a0, a1, 4);
    ACCC(c0, c1, 3); LDC(c0, c1, 5);
    ACCC(a0, a1, 4); LDC(a0, a1, 6);
    ACCC(c0, c1, 5); LDC(c0, c1, 7);
    ACCC(a0, a1, 6);
    ACCC(c0, c1, 7);
#undef LDC
#undef ACCC

    float lsum = 0.f;
#pragma unroll
    for (int j = 0; j < 8; ++j) lsum += log2f(s[j]);

    // class counts via ballot (wave-uniform), hoisted out of the hot loop
    int cntk[CLS];
#pragma unroll
    for (int k = 0; k < CLS; ++k) {
        int c8 = 0;
#pragma unroll
        for (int e = 0; e < 4; ++e) {
            c8 += __popcll(__ballot(t0[e] == k));
            c8 += __popcll(__ballot(t1[e] == k));
        }
        cntk[k] = c8;
    }

    // split-vector butterfly: lane l ends holding wave-total of entry bitrev6(l)
#pragma unroll
    for (int s6 = 0; s6 < 6; ++s6) {
        const int d = 1 << s6;
        const int half = 32 >> s6;
        const bool hi = (lane & d) != 0;
#pragma unroll
        for (int j = 0; j < half; ++j) {
            const float keep = hi ? acc[j + half] : acc[j];
            const float send = hi ? acc[j] : acc[j + half];
            acc[j] = keep + __shfl_xor(send, d);
        }
    }
    const int e6 = ((lane & 1) << 5) | ((lane & 2) << 3) | ((lane & 4) << 1) |
                   ((lane & 8) >> 1) | ((lane & 16) >> 3) | ((lane & 32) >> 5);

    __shared__ float redS[4][64];
    __shared__ float redl[4];
    __shared__ int   redc[4][CLS];

    redS[wv][e6] = acc[0];
    const float lw = wave_reduce(lsum);
    if (lane == 0) {
        redl[wv] = lw;
#pragma unroll
        for (int k = 0; k < CLS; ++k) redc[wv][k] = cntk[k];
    }
    __syncthreads();

    // plain coalesced stores to this block's private slot — zero contention
    float* slot = part + (size_t)(b * 128 + chunk) * SLOTF;
    if (tid < 64) {
        slot[tid] = redS[0][tid] + redS[1][tid] + redS[2][tid] + redS[3][tid];
    } else if (tid < 64 + CLS) {
        const int k = tid - 64;
        slot[tid] = (float)(redc[0][k] + redc[1][k] + redc[2][k] + redc[3][k]);
    } else if (tid == 64 + CLS) {
        slot[72] = (redl[0] + redl[1] + redl[2] + redl[3]) * LN2;
    }
}

// ---------------- finisher: 1 block, 1024 threads. Reduces 1024 slots (320 KB,
// coalesced, L2-resident) and runs the epilogue. No atomics anywhere. ----------
__global__ __launch_bounds__(1024) void jce_fin(
    const float* __restrict__ part, const float* __restrict__ w,
    float* __restrict__ out, int N)
{
    const int tid  = threadIdx.x;
    const int lane = tid & 63;
    const int wv   = tid >> 6;

    __shared__ float eS[BATCH][64];
    __shared__ float eN[BATCH][CLS];
    __shared__ float eLp[BATCH];
    __shared__ float eCe;

    if (tid < BATCH * SLOTF) {                  // 640 threads: (batch, column)
        const int b = tid / SLOTF, c = tid % SLOTF;
        if (c < 73) {
            const float* p = part + (size_t)(b * 128) * SLOTF + c;
            float acc = 0.f;
#pragma unroll 4
            for (int i = 0; i < 128; ++i) acc += p[(size_t)i * SLOTF];
            if (c < 64)      eS[b][c] = acc;
            else if (c < 72) eN[b][c - 64] = acc;
            else             eLp[b] = acc;
        }
    }
    __syncthreads();

    // ce = (sum lse - sum_b trace(S_b)) / (B*N)
    if (tid < 64) {
        const int bb = tid >> 3, kk = tid & 7;
        float tv = eS[bb][kk * 9];
        tv = wave_reduce(tv);
        if (tid == 0) {
            float el = 0.f;
#pragma unroll
            for (int b = 0; b < BATCH; ++b) el += eLp[b];
            eCe = (el - tv) / ((float)BATCH * (float)N);
        }
    }
    __syncthreads();

    // j[b] = -sum_{i!=k} w[i,k]*log(0.5 + 0.5*(A[i,i]-A[i,k])); out = j + ce
    if (wv < BATCH) {
        const int i = lane >> 3, k = lane & 7;
        const float A    = eS[wv][lane]  / eN[wv][k];
        const float diag = eS[wv][i * 9] / eN[wv][i];
        float term = 0.f;
        if (i != k)
            term = w[lane] * (log2f(0.5f + 0.5f * (diag - A)) * LN2);
        term = wave_reduce(term);
        if (lane == 0) out[wv] = -term + eCe;
    }
}

extern "C" void kernel_launch(void* const* d_in, const int* in_sizes, int n_in,
                              void* d_out, int out_size, void* d_ws, size_t ws_size,
                              hipStream_t stream) {
    const float* pred = (const float*)d_in[0];
    const int*   tgt  = (const int*)d_in[1];
    const float* w    = (const float*)d_in[2];
    float* out = (float*)d_out;

    const int N = in_sizes[1] / BATCH;        // H*W = 262144
    float* part = (float*)d_ws;               // 1024 * 80 floats, fully overwritten
                                              // every call -> no memset needed

    jce_main<<<dim3(BATCH * (N / SPAN)), dim3(256), 0, stream>>>(pred, tgt, part, N);
    jce_fin <<<dim3(1), dim3(1024), 0, stream>>>(part, w, out, N);
}